// Round 13
// baseline (2109.187 us; speedup 1.0000x reference)
//
#include <hip/hip_runtime.h>
#include <math.h>

// PLRNN forward via MFMA matvec, ASYMMETRIC wave specialization.
// 256 batches x 1024 steps, 1 WG (512 thr, 8 waves) per batch, 1 per CU.
// Waves 0-3 ("p1 waves") hold W2; waves 4-7 ("p2 waves") hold W1.
//   p1 wave w: pre rows [128w,128w+128) = 8mt x 4kt MFMA (C-in = h2),
//       bounce relu+f16 masked -> rt[128w..+128).          B0.
//   p2 wave w'=w-4: u rows [32w',32w'+32) over FULL K=512: 2mt x 16kt MFMA
//       + 2 tail MFMA ([C|h1] x [s~|1], built in-reg from Sc, issued PRE-B0
//       on the idle matrix pipe). Complete rows -> NO partial exchange.
//       update: zn = A*zf + u (A,zf in hc regs); TF via Xc; publish zf_h. B2.
// Only 4 waves read zf (16 LDS ops), only 4 read r (64 ops vs R4's 136);
// 2 barriers/step. Role-dependent register arrays are UNIONED (wf, hc) so
// both roles share one static allocation (~230 VGPR, no spill).
// X/S/out staged in LDS per 128-step chunk -> no global ops in steady state.

#define NB 256
#define T  1024
#define DX 64
#define DZ 128
#define DH 512
#define DS 16
#define CHUNK 128

typedef _Float16 half8 __attribute__((ext_vector_type(8)));
typedef _Float16 v4h   __attribute__((ext_vector_type(4)));
typedef float    f32x4 __attribute__((ext_vector_type(4)));

__device__ __forceinline__ half8 cvt8(const float* __restrict__ src) {
  const float4 a = *reinterpret_cast<const float4*>(src);
  const float4 c = *reinterpret_cast<const float4*>(src + 4);
  half8 h;
  h[0] = (_Float16)a.x; h[1] = (_Float16)a.y; h[2] = (_Float16)a.z; h[3] = (_Float16)a.w;
  h[4] = (_Float16)c.x; h[5] = (_Float16)c.y; h[6] = (_Float16)c.z; h[7] = (_Float16)c.w;
  return h;
}

__global__ __launch_bounds__(512, 2) void plrnn_kernel(
    const float* __restrict__ X, const float* __restrict__ S,
    const float* __restrict__ A, const float* __restrict__ W1,
    const float* __restrict__ W2, const float* __restrict__ h1,
    const float* __restrict__ h2, const float* __restrict__ C,
    float* __restrict__ out)
{
  __shared__ __align__(16) _Float16 zf_h[DZ];          // 256 B
  __shared__ __align__(16) _Float16 rt[DH];            // 1 KiB: relu(pre) f16
  __shared__ __align__(16) float    Xc[CHUNK][DX];     // 32 KiB: X[t+1 .. t+128]
  __shared__ __align__(16) float    Sc[CHUNK][DS];     // 8 KiB:  S[t .. t+127]
  __shared__ __align__(16) float    outc[CHUNK][DX];   // 32 KiB

  const int b   = blockIdx.x;
  const int tid = threadIdx.x;
  const int w   = tid >> 6;            // wave 0..7
  const int l   = tid & 63;
  const int g   = l >> 4;              // 16-lane group (k-slice group)
  const int r15 = l & 15;              // A row-in-tile / D col
  const int p1w = (w < 4);             // role
  const int w2  = w & 3;               // p2 wave index (w-4) / p1 wave index

  // ---- one-time: stage chunk 0 (X rows 1..128 clamped, S rows 0..127) ----
  {
    #pragma unroll
    for (int k = 0; k < 4; ++k) {
      const int flat = k * 2048 + tid * 4;
      int srow = 1 + (flat >> 6);
      if (srow > T - 1) srow = T - 1;
      const float4 v = *reinterpret_cast<const float4*>(X + ((size_t)b * T + srow) * DX + (flat & 63));
      *reinterpret_cast<float4*>(&((float*)Xc)[flat]) = v;
    }
    const int flat = tid * 4;
    const float4 v = *reinterpret_cast<const float4*>(S + ((size_t)b * T) * DS + flat);
    *reinterpret_cast<float4*>(&((float*)Sc)[flat]) = v;
  }

  // ---- one-time: UNIONED weight fragments ----
  // p1 waves: wf[mt*4+kt] = W2 rows 128w2+16mt+r15, k=32kt+8g+e  (mt<8,kt<4)
  // p2 waves: wf[mt*16+kt] = W1 rows 32w2+16mt+r15, k=32kt+8g+e  (mt<2,kt<16)
  half8 wf[32];
  if (p1w) {
    #pragma unroll
    for (int mt = 0; mt < 8; ++mt)
      #pragma unroll
      for (int kt = 0; kt < 4; ++kt)
        wf[mt * 4 + kt] = cvt8(W2 + ((size_t)b * DH + 128 * w2 + 16 * mt + r15) * DZ + 32 * kt + 8 * g);
  } else {
    #pragma unroll
    for (int mt = 0; mt < 2; ++mt)
      #pragma unroll
      for (int kt = 0; kt < 16; ++kt)
        wf[mt * 16 + kt] = cvt8(W1 + ((size_t)b * DZ + 32 * w2 + 16 * mt + r15) * DH + 32 * kt + 8 * g);
  }

  // ---- one-time: p2 tail fragments [C | h1] (zeros on p1 waves) ----
  half8 tailf[2];
  #pragma unroll
  for (int mt = 0; mt < 2; ++mt)
    #pragma unroll
    for (int e = 0; e < 8; ++e) tailf[mt][e] = (_Float16)0.0f;
  if (!p1w) {
    #pragma unroll
    for (int mt = 0; mt < 2; ++mt) {
      const int row = 32 * w2 + 16 * mt + r15;
      if (g == 0)      tailf[mt] = cvt8(C + ((size_t)b * DZ + row) * DS + 0);
      else if (g == 1) tailf[mt] = cvt8(C + ((size_t)b * DZ + row) * DS + 8);
      else if (g == 2) tailf[mt][0] = (_Float16)h1[(size_t)b * DZ + row];
    }
  }

  // ---- one-time: UNIONED per-role constants ----
  // p1: hc[0..7] = h2 rows 128w2+16mt+4g (acc C-in)
  // p2: hc[0..1] = A rows 32w2+16mt+4g; hc[2..3] = zfcur (mutable state)
  f32x4 hc[8];
  #pragma unroll
  for (int i = 0; i < 8; ++i) hc[i] = (f32x4){0.f, 0.f, 0.f, 0.f};
  if (p1w) {
    #pragma unroll
    for (int mt = 0; mt < 8; ++mt)
      hc[mt] = *reinterpret_cast<const f32x4*>(h2 + (size_t)b * DH + 128 * w2 + 16 * mt + 4 * g);
  } else {
    #pragma unroll
    for (int mt = 0; mt < 2; ++mt) {
      const int row = 32 * w2 + 16 * mt + 4 * g;
      hc[mt] = *reinterpret_cast<const f32x4*>(A + (size_t)b * DZ + row);
      f32x4 zf0 = {0.f, 0.f, 0.f, 0.f};
      if (row < DX) {
        const f32x4 x0 = *reinterpret_cast<const f32x4*>(X + ((size_t)b * T) * DX + row);
        #pragma unroll
        for (int j = 0; j < 4; ++j) zf0[j] = (x0[j] != x0[j]) ? 0.f : x0[j];  // zf(0)
      }
      hc[2 + mt] = zf0;
      if (r15 == 0) {
        v4h zp;
        #pragma unroll
        for (int j = 0; j < 4; ++j) zp[j] = (_Float16)zf0[j];
        *reinterpret_cast<v4h*>(&zf_h[row]) = zp;
      }
    }
  }
  __syncthreads();

  const f32x4 zero4 = {0.f, 0.f, 0.f, 0.f};

  for (int t = 0; t < T; ++t) {
    // ---- chunk boundary: flush out-chunk, stage next X/S chunk ----
    if ((t & (CHUNK - 1)) == 0 && t) {
      const int c0 = t - CHUNK;
      #pragma unroll
      for (int k = 0; k < 4; ++k) {
        const int flat = k * 2048 + tid * 4;
        const float4 v = *reinterpret_cast<const float4*>(&((float*)outc)[flat]);
        *reinterpret_cast<float4*>(out + ((size_t)b * T + c0) * DX + flat) = v;
      }
      #pragma unroll
      for (int k = 0; k < 4; ++k) {
        const int flat = k * 2048 + tid * 4;
        int srow = t + 1 + (flat >> 6);
        if (srow > T - 1) srow = T - 1;
        const float4 v = *reinterpret_cast<const float4*>(X + ((size_t)b * T + srow) * DX + (flat & 63));
        *reinterpret_cast<float4*>(&((float*)Xc)[flat]) = v;
      }
      {
        const int flat = tid * 4;
        const float4 v = *reinterpret_cast<const float4*>(S + ((size_t)b * T + t) * DS + flat);
        *reinterpret_cast<float4*>(&((float*)Sc)[flat]) = v;
      }
      __syncthreads();
    }
    const int tc = t & (CHUNK - 1);

    f32x4 tacc[2];                     // p2: C·s~ + h1 (pre-B0, off-chain)
    f32x4 xva[2];                      // p2: X[t+1] rows (pre-B0)

    if (p1w) {
      // ---- p1 phase: pre = h2 + W2·zf (32 MFMA, 8 chains of depth 4) ----
      half8 bz[4];
      #pragma unroll
      for (int kt = 0; kt < 4; ++kt)
        bz[kt] = *reinterpret_cast<const half8*>(zf_h + 32 * kt + 8 * g);

      f32x4 acc1[8];
      #pragma unroll
      for (int mt = 0; mt < 8; ++mt)
        acc1[mt] = __builtin_amdgcn_mfma_f32_16x16x32_f16(wf[mt * 4 + 0], bz[0], hc[mt], 0, 0, 0);
      #pragma unroll
      for (int kt = 1; kt < 4; ++kt)
        #pragma unroll
        for (int mt = 0; mt < 8; ++mt)
          acc1[mt] = __builtin_amdgcn_mfma_f32_16x16x32_f16(wf[mt * 4 + kt], bz[kt], acc1[mt], 0, 0, 0);

      // bounce (masked): relu+f16 -> rt[128w2+16mt+4g]
      if (r15 == 0) {
        #pragma unroll
        for (int mt = 0; mt < 8; ++mt) {
          v4h p;
          p[0] = (_Float16)fmaxf(acc1[mt][0], 0.f);
          p[1] = (_Float16)fmaxf(acc1[mt][1], 0.f);
          p[2] = (_Float16)fmaxf(acc1[mt][2], 0.f);
          p[3] = (_Float16)fmaxf(acc1[mt][3], 0.f);
          *reinterpret_cast<v4h*>(&rt[128 * w2 + 16 * mt + 4 * g]) = p;
        }
      }
    } else {
      // ---- p2 pre-B0: build s~ in reg, issue tail MFMAs; prefetch X[t+1] ----
      half8 brt;
      {
        const f32x4 sa0 = *reinterpret_cast<const f32x4*>(&Sc[tc][8 * (g & 1)]);
        const f32x4 sa1 = *reinterpret_cast<const f32x4*>(&Sc[tc][8 * (g & 1) + 4]);
        #pragma unroll
        for (int e = 0; e < 4; ++e) {
          brt[e]     = (g < 2) ? (_Float16)sa0[e] : (_Float16)0.0f;
          brt[e + 4] = (g < 2) ? (_Float16)sa1[e] : (_Float16)0.0f;
        }
        if (g == 2) brt[0] = (_Float16)1.0f;   // h1 column multiplier
      }
      #pragma unroll
      for (int mt = 0; mt < 2; ++mt)
        tacc[mt] = __builtin_amdgcn_mfma_f32_16x16x32_f16(tailf[mt], brt, zero4, 0, 0, 0);
      if (w2 < 2) {
        #pragma unroll
        for (int mt = 0; mt < 2; ++mt)
          xva[mt] = *reinterpret_cast<const f32x4*>(&Xc[tc][32 * w2 + 16 * mt + 4 * g]);
      }
    }
    __syncthreads();   // B0: r complete

    if (!p1w) {
      // ---- p2 phase: u rows [32w2,32w2+32) over full K (32 MFMA) ----
      f32x4 acc2[8];   // [mt*4 + chain]
      #pragma unroll
      for (int mt = 0; mt < 2; ++mt) {
        acc2[mt * 4 + 0] = tacc[mt];
        acc2[mt * 4 + 1] = zero4;
        acc2[mt * 4 + 2] = zero4;
        acc2[mt * 4 + 3] = zero4;
      }
      #pragma unroll
      for (int kt = 0; kt < 16; ++kt) {
        const half8 br = *reinterpret_cast<const half8*>(rt + 32 * kt + 8 * g);
        acc2[0 * 4 + (kt & 3)] = __builtin_amdgcn_mfma_f32_16x16x32_f16(wf[0 * 16 + kt], br, acc2[0 * 4 + (kt & 3)], 0, 0, 0);
        acc2[1 * 4 + (kt & 3)] = __builtin_amdgcn_mfma_f32_16x16x32_f16(wf[1 * 16 + kt], br, acc2[1 * 4 + (kt & 3)], 0, 0, 0);
      }

      // ---- update (masked r15==0): zn = A*zf + u; TF; publish ----
      if (r15 == 0) {
        #pragma unroll
        for (int mt = 0; mt < 2; ++mt) {
          const int row = 32 * w2 + 16 * mt + 4 * g;
          const f32x4 u = (acc2[mt * 4 + 0] + acc2[mt * 4 + 1])
                        + (acc2[mt * 4 + 2] + acc2[mt * 4 + 3]);
          f32x4 zn, zfn;
          #pragma unroll
          for (int j = 0; j < 4; ++j) zn[j] = hc[mt][j] * hc[2 + mt][j] + u[j];
          zfn = zn;
          if (w2 < 2) {
            *reinterpret_cast<f32x4*>(&outc[tc][row]) = zn;
            #pragma unroll
            for (int j = 0; j < 4; ++j)
              zfn[j] = (xva[mt][j] != xva[mt][j]) ? zn[j]
                     : (0.125f * xva[mt][j] + 0.875f * zn[j]);
          }
          hc[2 + mt] = zfn;
          v4h zp;
          #pragma unroll
          for (int j = 0; j < 4; ++j) zp[j] = (_Float16)zfn[j];
          *reinterpret_cast<v4h*>(&zf_h[row]) = zp;
        }
      }
    }
    __syncthreads();   // B2: zf(t+1) visible
  }

  // ---- final flush (last chunk) ----
  {
    const int c0 = T - CHUNK;
    #pragma unroll
    for (int k = 0; k < 4; ++k) {
      const int flat = k * 2048 + tid * 4;
      const float4 v = *reinterpret_cast<const float4*>(&((float*)outc)[flat]);
      *reinterpret_cast<float4*>(out + ((size_t)b * T + c0) * DX + flat) = v;
    }
  }
}

extern "C" void kernel_launch(void* const* d_in, const int* in_sizes, int n_in,
                              void* d_out, int out_size, void* d_ws, size_t ws_size,
                              hipStream_t stream) {
  const float* X  = (const float*)d_in[0];
  const float* S  = (const float*)d_in[1];
  const float* A  = (const float*)d_in[2];
  const float* W1 = (const float*)d_in[3];
  const float* W2 = (const float*)d_in[4];
  const float* h1 = (const float*)d_in[5];
  const float* h2 = (const float*)d_in[6];
  const float* C  = (const float*)d_in[7];
  float* out = (float*)d_out;
  plrnn_kernel<<<dim3(NB), dim3(512), 0, stream>>>(X, S, A, W1, W2, h1, h2, C, out);
}